// Round 8
// baseline (391.996 us; speedup 1.0000x reference)
//
#include <hip/hip_runtime.h>
#include <hip/hip_bf16.h>
#include <hip/hip_cooperative_groups.h>

namespace cg = cooperative_groups;

typedef __attribute__((ext_vector_type(8))) short short8;
typedef __attribute__((ext_vector_type(4))) float f32x4;

#define NNODES 8192
#define FDIM 128

// ---------------- helpers ----------------
static __device__ inline unsigned short f2bf(float f) {
    union { float f; unsigned int u; } a; a.f = f;
    unsigned int u = a.u;
    unsigned int r = u + 0x7FFFu + ((u >> 16) & 1u);
    return (unsigned short)(r >> 16);
}

// ---------------- shared phase bodies (used by coop kernel AND fallback) ----------
// linear: Y[row] = (X[row] @ W) * norm[row]; 16 rows/tile, X-tile in LDS.
template<int K>
__device__ void lin_phase(const float* __restrict__ X, const float* __restrict__ W,
                          const float* __restrict__ norm, float* __restrict__ Y,
                          float* xs) {
    const int t = threadIdx.x;
    constexpr int K4 = K / 4;
    constexpr int NCH = 16 * K4 / 256;
    for (int tile = blockIdx.x; tile < NNODES / 16; tile += gridDim.x) {
        int row0 = tile * 16;
        __syncthreads();
#pragma unroll
        for (int i = 0; i < NCH; ++i) {
            int c = t + i * 256;
            int r = c / K4, k4 = c % K4;
            *(float4*)&xs[r * K + k4 * 4] = *(const float4*)(X + (size_t)(row0 + r) * K + k4 * 4);
        }
        __syncthreads();
        int lane = t & 31, g = t >> 5;
        int r0 = g * 2, r1 = r0 + 1;
        int c = lane * 4;
        f32x4 acc0 = {0.f, 0.f, 0.f, 0.f}, acc1 = {0.f, 0.f, 0.f, 0.f};
        for (int k = 0; k < K; k += 4) {
            f32x4 x0 = *(f32x4*)&xs[r0 * K + k];
            f32x4 x1 = *(f32x4*)&xs[r1 * K + k];
#pragma unroll
            for (int kk = 0; kk < 4; ++kk) {
                f32x4 w = *(const f32x4*)(W + (size_t)(k + kk) * FDIM + c);
                acc0 += w * x0[kk];
                acc1 += w * x1[kk];
            }
        }
        float n0 = norm[row0 + r0], n1 = norm[row0 + r1];
        *(f32x4*)(Y + (size_t)(row0 + r0) * FDIM + c) = acc0 * n0;
        *(f32x4*)(Y + (size_t)(row0 + r1) * FDIM + c) = acc1 * n1;
    }
}

// gather: out = act( (sum_e Y[csr_src[e]]) * rsqrt(deg) + bias ); 32 lanes/node.
template<int MODE>  // 0: relu -> f32; 1: identity -> bf16
__device__ void gather_phase(const float* __restrict__ Y, const int* __restrict__ row_start,
                             const int* __restrict__ csr_src, const float* __restrict__ bias,
                             void* __restrict__ outp) {
    const int t = threadIdx.x;
    const int c4 = (t & 31) << 2;
    for (int node0 = blockIdx.x * 8; node0 < NNODES; node0 += gridDim.x * 8) {
        int node = node0 + (t >> 5);
        int beg = row_start[node], end = row_start[node + 1];
        f32x4 acc0 = {0.f, 0.f, 0.f, 0.f}, acc1 = {0.f, 0.f, 0.f, 0.f};
        int e = beg;
        for (; e + 3 < end; e += 4) {
            int s0 = csr_src[e], s1 = csr_src[e + 1], s2 = csr_src[e + 2], s3 = csr_src[e + 3];
            f32x4 v0 = *(const f32x4*)(Y + ((size_t)s0 << 7) + c4);
            f32x4 v1 = *(const f32x4*)(Y + ((size_t)s1 << 7) + c4);
            f32x4 v2 = *(const f32x4*)(Y + ((size_t)s2 << 7) + c4);
            f32x4 v3 = *(const f32x4*)(Y + ((size_t)s3 << 7) + c4);
            acc0 += v0; acc1 += v1; acc0 += v2; acc1 += v3;
        }
        for (; e < end; ++e) {
            int s0 = csr_src[e];
            acc0 += *(const f32x4*)(Y + ((size_t)s0 << 7) + c4);
        }
        f32x4 acc = acc0 + acc1;
        float scale = rsqrtf(fmaxf((float)(end - beg), 1.0f));
        f32x4 b = *(const f32x4*)(bias + c4);
        f32x4 v = acc * scale + b;
        if (MODE == 0) {
#pragma unroll
            for (int i = 0; i < 4; ++i) v[i] = fmaxf(v[i], 0.f);
            *(f32x4*)((float*)outp + ((size_t)node << 7) + c4) = v;
        } else {
            ushort4 u;
            u.x = f2bf(v[0]); u.y = f2bf(v[1]); u.z = f2bf(v[2]); u.w = f2bf(v[3]);
            *(ushort4*)((unsigned short*)outp + ((size_t)node << 7) + c4) = u;
        }
    }
}

// ---------------- single cooperative encode kernel (256 blocks) ----------------
struct EncArgs {
    const int* src; const int* dst; int E;
    int* cnt;            // cnt_s = cnt[0..N), cnt_d = cnt[N..2N)
    float* norm_s; int* row_start; int* cursor; int* csr_src;
    const float* x; const float* W1; const float* b1;
    const float* W2; const float* b2;
    float* bufA; float* bufB; unsigned short* h2;
};

__global__ __launch_bounds__(256) void k_encode(EncArgs a) {
    cg::grid_group grid = cg::this_grid();
    __shared__ __align__(16) float xs[16 * 256];  // 16KB; aliased by scan
    const int t = threadIdx.x;
    const int gid = blockIdx.x * 256 + t;
    const int gsz = gridDim.x * 256;

    // P0: zero degree counters
    for (int i = gid; i < 2 * NNODES; i += gsz) a.cnt[i] = 0;
    grid.sync();

    // P1: count degrees
    for (int e = gid; e < a.E; e += gsz) {
        atomicAdd(&a.cnt[a.src[e]], 1);
        atomicAdd(&a.cnt[NNODES + a.dst[e]], 1);
    }
    grid.sync();

    // P2: norm_s (all blocks) + exclusive scan of cnt_d (block 0)
    for (int i = gid; i < NNODES; i += gsz)
        a.norm_s[i] = rsqrtf(fmaxf((float)a.cnt[i], 1.0f));
    if (blockIdx.x == 0) {
        int* partial = (int*)xs;
        int* offs = partial + 256;
        const int* cnt_d = a.cnt + NNODES;
        int base = t * 32;
        int local[32];
        int s = 0;
#pragma unroll
        for (int i = 0; i < 32; ++i) { local[i] = s; s += cnt_d[base + i]; }
        partial[t] = s;
        __syncthreads();
        if (t == 0) {
            int acc = 0;
            for (int i = 0; i < 256; ++i) { offs[i] = acc; acc += partial[i]; }
            offs[256] = acc;
        }
        __syncthreads();
        int o = offs[t];
#pragma unroll
        for (int i = 0; i < 32; ++i) {
            int v = o + local[i];
            a.row_start[base + i] = v;
            a.cursor[base + i] = v;
        }
        if (t == 0) a.row_start[NNODES] = offs[256];
    }
    grid.sync();

    // P3: CSR fill + linear1 (independent; both complete before gather1)
    for (int e = gid; e < a.E; e += gsz) {
        int pos = atomicAdd(&a.cursor[a.dst[e]], 1);
        a.csr_src[pos] = a.src[e];
    }
    lin_phase<256>(a.x, a.W1, a.norm_s, a.bufA, xs);
    grid.sync();

    // P4: gather1 -> h1 = relu(...) into bufB (f32)
    gather_phase<0>(a.bufA, a.row_start, a.csr_src, a.b1, a.bufB);
    grid.sync();

    // P5: linear2
    lin_phase<128>(a.bufB, a.W2, a.norm_s, a.bufA, xs);
    grid.sync();

    // P6: gather2 -> h2 (bf16)
    gather_phase<1>(a.bufA, a.row_start, a.csr_src, a.b2, a.h2);
}

// ---------------- fallback standalone kernels (r3-proven structure) ----------------
__global__ void k_zero(int* __restrict__ p, int n) {
    int i = blockIdx.x * blockDim.x + threadIdx.x;
    if (i < n) p[i] = 0;
}

__global__ void k_deg_int(const int* __restrict__ src, const int* __restrict__ dst,
                          int* __restrict__ cnt, int E) {
    int e = blockIdx.x * blockDim.x + threadIdx.x;
    if (e < E) {
        atomicAdd(&cnt[src[e]], 1);
        atomicAdd(&cnt[NNODES + dst[e]], 1);
    }
}

__global__ __launch_bounds__(256) void k_scan_norms(const int* __restrict__ cnt,
                                                    float* __restrict__ norm_s,
                                                    int* __restrict__ row_start,
                                                    int* __restrict__ cursor, int n) {
    __shared__ int partial[256];
    __shared__ int offs[257];
    int t = threadIdx.x;
    int base = t * 32;
    const int* cnt_d = cnt + NNODES;
#pragma unroll
    for (int i = 0; i < 32; ++i)
        norm_s[base + i] = rsqrtf(fmaxf((float)cnt[base + i], 1.0f));
    int local[32];
    int s = 0;
#pragma unroll
    for (int i = 0; i < 32; ++i) { local[i] = s; s += cnt_d[base + i]; }
    partial[t] = s;
    __syncthreads();
    if (t == 0) {
        int acc = 0;
        for (int i = 0; i < 256; ++i) { offs[i] = acc; acc += partial[i]; }
        offs[256] = acc;
    }
    __syncthreads();
    int o = offs[t];
#pragma unroll
    for (int i = 0; i < 32; ++i) {
        int v = o + local[i];
        row_start[base + i] = v;
        cursor[base + i] = v;
    }
    if (t == 0) row_start[n] = offs[256];
}

__global__ void k_fill(const int* __restrict__ src, const int* __restrict__ dst,
                       int* __restrict__ cursor, int* __restrict__ csr_src, int E) {
    int e = blockIdx.x * blockDim.x + threadIdx.x;
    if (e < E) {
        int pos = atomicAdd(&cursor[dst[e]], 1);
        csr_src[pos] = src[e];
    }
}

template<int K>
__global__ __launch_bounds__(256) void k_lin(const float* __restrict__ X,
                                             const float* __restrict__ W,
                                             const float* __restrict__ norm,
                                             float* __restrict__ Y) {
    __shared__ __align__(16) float xs[16 * K];
    lin_phase<K>(X, W, norm, Y, xs);
}

template<int MODE>
__global__ __launch_bounds__(256) void k_gat(const float* __restrict__ Y,
                                             const int* __restrict__ row_start,
                                             const int* __restrict__ csr_src,
                                             const float* __restrict__ bias,
                                             void* __restrict__ outp) {
    gather_phase<MODE>(Y, row_start, csr_src, bias, outp);
}

// ---------------- decode: C = sigmoid(H @ H^T), H is [8192][128] bf16 ----------------
// 128x128 tile/block, 4 waves, mfma_f32_16x16x32_bf16, XOR-swizzled LDS,
// rcp-based sigmoid, plain dword stores (r3-proven pattern).
__global__ __launch_bounds__(256) void k_decode(const __hip_bfloat16* __restrict__ H,
                                                float* __restrict__ C) {
    __shared__ __align__(16) unsigned char smem[65536];
    unsigned char* sA = smem;
    unsigned char* sB = smem + 32768;
    const int ti = blockIdx.x, tj = blockIdx.y;
    const int t = threadIdx.x;
    const unsigned char* gH = (const unsigned char*)H;

#pragma unroll
    for (int i = 0; i < 8; ++i) {
        int chunk = t + i * 256;
        int row = chunk >> 4;
        int cc = (chunk & 15) << 4;
        int lofs = row * 256 + (cc ^ ((row & 7) << 4));
        *(float4*)(sA + lofs) = *(const float4*)(gH + ((size_t)(ti * 128 + row) << 8) + cc);
        *(float4*)(sB + lofs) = *(const float4*)(gH + ((size_t)(tj * 128 + row) << 8) + cc);
    }
    __syncthreads();

    const int w = t >> 6, lane = t & 63;
    const int wr = (w >> 1) * 64, wc = (w & 1) * 64;
    const int lr = lane & 15;
    const int lk = (lane >> 4) * 16;

    f32x4 acc[4][4] = {};

#pragma unroll
    for (int ks = 0; ks < 4; ++ks) {
        short8 af[4], bfr[4];
#pragma unroll
        for (int mi = 0; mi < 4; ++mi) {
            int row = wr + mi * 16 + lr;
            int off = row * 256 + ((ks * 64 + lk) ^ ((row & 7) << 4));
            af[mi] = *(const short8*)(sA + off);
        }
#pragma unroll
        for (int ni = 0; ni < 4; ++ni) {
            int row = wc + ni * 16 + lr;
            int off = row * 256 + ((ks * 64 + lk) ^ ((row & 7) << 4));
            bfr[ni] = *(const short8*)(sB + off);
        }
#pragma unroll
        for (int mi = 0; mi < 4; ++mi)
#pragma unroll
            for (int ni = 0; ni < 4; ++ni)
                acc[mi][ni] = __builtin_amdgcn_mfma_f32_16x16x32_bf16(af[mi], bfr[ni],
                                                                      acc[mi][ni], 0, 0, 0);
    }

    // C/D layout: col=lane&15, row=(lane>>4)*4+r (m89)
    const int rbase = (lane >> 4) * 4;
    const int cbase = lane & 15;
#pragma unroll
    for (int mi = 0; mi < 4; ++mi) {
        int rowb = ti * 128 + wr + mi * 16 + rbase;
#pragma unroll
        for (int ni = 0; ni < 4; ++ni) {
            int col = tj * 128 + wc + ni * 16 + cbase;
#pragma unroll
            for (int r = 0; r < 4; ++r) {
                float s = __builtin_amdgcn_rcpf(1.0f + __expf(-acc[mi][ni][r]));
                C[(size_t)(rowb + r) * NNODES + col] = s;
            }
        }
    }
}

extern "C" void kernel_launch(void* const* d_in, const int* in_sizes, int n_in,
                              void* d_out, int out_size, void* d_ws, size_t ws_size,
                              hipStream_t stream) {
    const float* x  = (const float*)d_in[0];
    const int* src  = (const int*)d_in[1];
    const int* dst  = (const int*)d_in[2];
    const float* W1 = (const float*)d_in[3];
    const float* b1 = (const float*)d_in[4];
    const float* W2 = (const float*)d_in[5];
    const float* b2 = (const float*)d_in[6];
    float* out = (float*)d_out;
    const int E = in_sizes[1];

    char* ws = (char*)d_ws;
    float* norm_s    = (float*)(ws + 0);                // 32KB
    int*   cnt       = (int*)(ws + (32 << 10));         // 64KB (cnt_s | cnt_d)
    int*   row_start = (int*)(ws + (96 << 10));         // 8193 ints
    int*   cursor    = (int*)(ws + (132 << 10));        // 32KB
    int*   csr_src   = (int*)(ws + (164 << 10));        // E ints = 1MB
    char*  big       = ws + (164 << 10) + ((size_t)E * 4);
    float* bufA      = (float*)big;                     // 4MB
    float* bufB      = (float*)(big + (4 << 20));       // 4MB
    __hip_bfloat16* h2bf = (__hip_bfloat16*)(big + (8 << 20));  // 2MB

    EncArgs ea;
    ea.src = src; ea.dst = dst; ea.E = E;
    ea.cnt = cnt; ea.norm_s = norm_s; ea.row_start = row_start;
    ea.cursor = cursor; ea.csr_src = csr_src;
    ea.x = x; ea.W1 = W1; ea.b1 = b1; ea.W2 = W2; ea.b2 = b2;
    ea.bufA = bufA; ea.bufB = bufB; ea.h2 = (unsigned short*)h2bf;

    void* kp[] = { &ea };
    hipError_t cerr = hipLaunchCooperativeKernel((const void*)k_encode, dim3(256), dim3(256),
                                                 kp, 0, stream);
    if (cerr != hipSuccess) {
        (void)hipGetLastError();  // clear error state, use proven multi-kernel path
        k_zero<<<(2 * NNODES + 255) / 256, 256, 0, stream>>>(cnt, 2 * NNODES);
        k_deg_int<<<(E + 255) / 256, 256, 0, stream>>>(src, dst, cnt, E);
        k_scan_norms<<<1, 256, 0, stream>>>(cnt, norm_s, row_start, cursor, NNODES);
        k_fill<<<(E + 255) / 256, 256, 0, stream>>>(src, dst, cursor, csr_src, E);
        k_lin<256><<<NNODES / 16, 256, 0, stream>>>(x, W1, norm_s, bufA);
        k_gat<0><<<NNODES / 8, 256, 0, stream>>>(bufA, row_start, csr_src, b1, bufB);
        k_lin<128><<<NNODES / 16, 256, 0, stream>>>(bufB, W2, norm_s, bufA);
        k_gat<1><<<NNODES / 8, 256, 0, stream>>>(bufA, row_start, csr_src, b2, h2bf);
    }

    // decode: out = sigmoid(h2 @ h2^T)
    k_decode<<<dim3(64, 64), 256, 0, stream>>>(h2bf, out);
}

// Round 9
// 177.456 us; speedup vs baseline: 2.2090x; 2.2090x over previous
//
#include <hip/hip_runtime.h>
#include <hip/hip_bf16.h>

typedef __attribute__((ext_vector_type(8))) short short8;
typedef __attribute__((ext_vector_type(4))) float f32x4;

#define NNODES 8192
#define FDIM 128

// ---------------- helpers ----------------
static __device__ inline unsigned short f2bf(float f) {
    union { float f; unsigned int u; } a; a.f = f;
    unsigned int u = a.u;
    unsigned int r = u + 0x7FFFu + ((u >> 16) & 1u);
    return (unsigned short)(r >> 16);
}

// ---------------- zero ints ----------------
__global__ void k_zero(int* __restrict__ p, int n) {
    int i = blockIdx.x * blockDim.x + threadIdx.x;
    if (i < n) p[i] = 0;
}

// ---------------- degree count (cnt_s | cnt_d in one array) ----------------
__global__ void k_deg_int(const int* __restrict__ src, const int* __restrict__ dst,
                          int* __restrict__ cnt, int E) {
    int e = blockIdx.x * blockDim.x + threadIdx.x;
    if (e < E) {
        atomicAdd(&cnt[src[e]], 1);
        atomicAdd(&cnt[NNODES + dst[e]], 1);
    }
}

// ---------------- single-block: norm_s + exclusive scan over cnt_d ----------------
__global__ __launch_bounds__(256) void k_scan_norms(const int* __restrict__ cnt,
                                                    float* __restrict__ norm_s,
                                                    int* __restrict__ row_start,
                                                    int* __restrict__ cursor, int n) {
    __shared__ int partial[256];
    __shared__ int offs[257];
    int t = threadIdx.x;
    int base = t * 32;
    const int* cnt_d = cnt + NNODES;
#pragma unroll
    for (int i = 0; i < 32; ++i)
        norm_s[base + i] = rsqrtf(fmaxf((float)cnt[base + i], 1.0f));
    int local[32];
    int s = 0;
#pragma unroll
    for (int i = 0; i < 32; ++i) { local[i] = s; s += cnt_d[base + i]; }
    partial[t] = s;
    __syncthreads();
    if (t == 0) {
        int acc = 0;
        for (int i = 0; i < 256; ++i) { offs[i] = acc; acc += partial[i]; }
        offs[256] = acc;
    }
    __syncthreads();
    int o = offs[t];
#pragma unroll
    for (int i = 0; i < 32; ++i) {
        int v = o + local[i];
        row_start[base + i] = v;
        cursor[base + i] = v;
    }
    if (t == 0) row_start[n] = offs[256];
}

__global__ void k_fill(const int* __restrict__ src, const int* __restrict__ dst,
                       int* __restrict__ cursor, int* __restrict__ csr_src, int E) {
    int e = blockIdx.x * blockDim.x + threadIdx.x;
    if (e < E) {
        int pos = atomicAdd(&cursor[dst[e]], 1);
        csr_src[pos] = src[e];
    }
}

// ---------------- linear1: Y[row] = (X[row] @ W) * norm[row], K=256 ----------------
template<int K>
__global__ __launch_bounds__(256) void k_lin(const float* __restrict__ X,
                                             const float* __restrict__ W,
                                             const float* __restrict__ norm,
                                             float* __restrict__ Y) {
    __shared__ float xs[16][K];
    int t = threadIdx.x;
    int row0 = blockIdx.x * 16;
    constexpr int K4 = K / 4;
    constexpr int NCH = 16 * K4 / 256;
#pragma unroll
    for (int i = 0; i < NCH; ++i) {
        int c = t + i * 256;
        int r = c / K4, k4 = c % K4;
        *(float4*)&xs[r][k4 * 4] = *(const float4*)(X + (size_t)(row0 + r) * K + k4 * 4);
    }
    __syncthreads();

    int lane = t & 31, g = t >> 5;
    int r0 = g * 2, r1 = r0 + 1;
    int c = lane * 4;
    f32x4 acc0 = {0.f, 0.f, 0.f, 0.f}, acc1 = {0.f, 0.f, 0.f, 0.f};
    for (int k = 0; k < K; k += 4) {
        f32x4 x0 = *(f32x4*)&xs[r0][k];
        f32x4 x1 = *(f32x4*)&xs[r1][k];
#pragma unroll
        for (int kk = 0; kk < 4; ++kk) {
            f32x4 w = *(const f32x4*)(W + (size_t)(k + kk) * FDIM + c);
            acc0 += w * x0[kk];
            acc1 += w * x1[kk];
        }
    }
    float n0 = norm[row0 + r0], n1 = norm[row0 + r1];
    *(f32x4*)(Y + (size_t)(row0 + r0) * FDIM + c) = acc0 * n0;
    *(f32x4*)(Y + (size_t)(row0 + r1) * FDIM + c) = acc1 * n1;
}

// ---------------- fused gather1 + linear2 ----------------
// 8 nodes/block, 32 lanes/node. Gather h1 rows into LDS (relu'd), then
// y2[row] = (h1[row] @ W2) * norm_s[row] for the same 8 rows (block-local).
// Eliminates the 4MB h1 buffer round-trip and one dispatch.
__global__ __launch_bounds__(256) void k_gatlin(const float* __restrict__ Y,
                                                const int* __restrict__ row_start,
                                                const int* __restrict__ csr_src,
                                                const float* __restrict__ b1,
                                                const float* __restrict__ W2,
                                                const float* __restrict__ norm_s,
                                                float* __restrict__ Y2) {
    __shared__ float h1s[8][132];  // +4 pad
    const int t = threadIdx.x;
    const int g = t >> 5, lane = t & 31;
    const int node = blockIdx.x * 8 + g;
    const int c4 = lane << 2;

    // gather phase (r3-proven body)
    int beg = row_start[node], end = row_start[node + 1];
    f32x4 acc0 = {0.f, 0.f, 0.f, 0.f}, acc1 = {0.f, 0.f, 0.f, 0.f};
    int e = beg;
    for (; e + 3 < end; e += 4) {
        int s0 = csr_src[e], s1 = csr_src[e + 1], s2 = csr_src[e + 2], s3 = csr_src[e + 3];
        f32x4 v0 = *(const f32x4*)(Y + ((size_t)s0 << 7) + c4);
        f32x4 v1 = *(const f32x4*)(Y + ((size_t)s1 << 7) + c4);
        f32x4 v2 = *(const f32x4*)(Y + ((size_t)s2 << 7) + c4);
        f32x4 v3 = *(const f32x4*)(Y + ((size_t)s3 << 7) + c4);
        acc0 += v0; acc1 += v1; acc0 += v2; acc1 += v3;
    }
    for (; e < end; ++e) {
        int s0 = csr_src[e];
        acc0 += *(const f32x4*)(Y + ((size_t)s0 << 7) + c4);
    }
    f32x4 acc = acc0 + acc1;
    float scale = rsqrtf(fmaxf((float)(end - beg), 1.0f));
    f32x4 b = *(const f32x4*)(b1 + c4);
    f32x4 v = acc * scale + b;
#pragma unroll
    for (int i = 0; i < 4; ++i) v[i] = fmaxf(v[i], 0.f);
    *(f32x4*)&h1s[g][c4] = v;
    __syncthreads();

    // linear2 phase: row g, cols c4..c4+3 (h1s[g][k] is a wave-broadcast read)
    f32x4 acc2 = {0.f, 0.f, 0.f, 0.f};
    for (int k = 0; k < FDIM; k += 4) {
        f32x4 xv = *(f32x4*)&h1s[g][k];
#pragma unroll
        for (int kk = 0; kk < 4; ++kk) {
            f32x4 w = *(const f32x4*)(W2 + (size_t)(k + kk) * FDIM + c4);
            acc2 += w * xv[kk];
        }
    }
    float ns = norm_s[node];
    *(f32x4*)(Y2 + ((size_t)node << 7) + c4) = acc2 * ns;
}

// ---------------- gather2: h2 = bf16( gather(y2)*nd + b2 ) ----------------
__global__ __launch_bounds__(256) void k_gat2(const float* __restrict__ Y,
                                              const int* __restrict__ row_start,
                                              const int* __restrict__ csr_src,
                                              const float* __restrict__ bias,
                                              unsigned short* __restrict__ outp) {
    int t = threadIdx.x;
    int node = blockIdx.x * 8 + (t >> 5);
    int c4 = (t & 31) << 2;
    int beg = row_start[node], end = row_start[node + 1];
    f32x4 acc0 = {0.f, 0.f, 0.f, 0.f}, acc1 = {0.f, 0.f, 0.f, 0.f};
    int e = beg;
    for (; e + 3 < end; e += 4) {
        int s0 = csr_src[e], s1 = csr_src[e + 1], s2 = csr_src[e + 2], s3 = csr_src[e + 3];
        f32x4 v0 = *(const f32x4*)(Y + ((size_t)s0 << 7) + c4);
        f32x4 v1 = *(const f32x4*)(Y + ((size_t)s1 << 7) + c4);
        f32x4 v2 = *(const f32x4*)(Y + ((size_t)s2 << 7) + c4);
        f32x4 v3 = *(const f32x4*)(Y + ((size_t)s3 << 7) + c4);
        acc0 += v0; acc1 += v1; acc0 += v2; acc1 += v3;
    }
    for (; e < end; ++e) {
        int s0 = csr_src[e];
        acc0 += *(const f32x4*)(Y + ((size_t)s0 << 7) + c4);
    }
    f32x4 acc = acc0 + acc1;
    float scale = rsqrtf(fmaxf((float)(end - beg), 1.0f));
    f32x4 b = *(const f32x4*)(bias + c4);
    f32x4 v = acc * scale + b;
    ushort4 u;
    u.x = f2bf(v[0]); u.y = f2bf(v[1]); u.z = f2bf(v[2]); u.w = f2bf(v[3]);
    *(ushort4*)(outp + ((size_t)node << 7) + c4) = u;
}

// ---------------- decode: C = sigmoid(H @ H^T), H is [8192][128] bf16 ----------------
// 128x128 tile/block, 4 waves, mfma_f32_16x16x32_bf16, XOR-swizzled LDS,
// rcp-based sigmoid (validated r6/r8: absmax unchanged), plain dword stores.
__global__ __launch_bounds__(256) void k_decode(const __hip_bfloat16* __restrict__ H,
                                                float* __restrict__ C) {
    __shared__ __align__(16) unsigned char smem[65536];
    unsigned char* sA = smem;
    unsigned char* sB = smem + 32768;
    const int ti = blockIdx.x, tj = blockIdx.y;
    const int t = threadIdx.x;
    const unsigned char* gH = (const unsigned char*)H;

#pragma unroll
    for (int i = 0; i < 8; ++i) {
        int chunk = t + i * 256;
        int row = chunk >> 4;
        int cc = (chunk & 15) << 4;
        int lofs = row * 256 + (cc ^ ((row & 7) << 4));
        *(float4*)(sA + lofs) = *(const float4*)(gH + ((size_t)(ti * 128 + row) << 8) + cc);
        *(float4*)(sB + lofs) = *(const float4*)(gH + ((size_t)(tj * 128 + row) << 8) + cc);
    }
    __syncthreads();

    const int w = t >> 6, lane = t & 63;
    const int wr = (w >> 1) * 64, wc = (w & 1) * 64;
    const int lr = lane & 15;
    const int lk = (lane >> 4) * 16;

    f32x4 acc[4][4] = {};

#pragma unroll
    for (int ks = 0; ks < 4; ++ks) {
        short8 af[4], bfr[4];
#pragma unroll
        for (int mi = 0; mi < 4; ++mi) {
            int row = wr + mi * 16 + lr;
            int off = row * 256 + ((ks * 64 + lk) ^ ((row & 7) << 4));
            af[mi] = *(const short8*)(sA + off);
        }
#pragma unroll
        for (int ni = 0; ni < 4; ++ni) {
            int row = wc + ni * 16 + lr;
            int off = row * 256 + ((ks * 64 + lk) ^ ((row & 7) << 4));
            bfr[ni] = *(const short8*)(sB + off);
        }
#pragma unroll
        for (int mi = 0; mi < 4; ++mi)
#pragma unroll
            for (int ni = 0; ni < 4; ++ni)
                acc[mi][ni] = __builtin_amdgcn_mfma_f32_16x16x32_bf16(af[mi], bfr[ni],
                                                                      acc[mi][ni], 0, 0, 0);
    }

    // C/D layout: col=lane&15, row=(lane>>4)*4+r (m89)
    const int rbase = (lane >> 4) * 4;
    const int cbase = lane & 15;
#pragma unroll
    for (int mi = 0; mi < 4; ++mi) {
        int rowb = ti * 128 + wr + mi * 16 + rbase;
#pragma unroll
        for (int ni = 0; ni < 4; ++ni) {
            int col = tj * 128 + wc + ni * 16 + cbase;
#pragma unroll
            for (int r = 0; r < 4; ++r) {
                float s = __builtin_amdgcn_rcpf(1.0f + __expf(-acc[mi][ni][r]));
                C[(size_t)(rowb + r) * NNODES + col] = s;
            }
        }
    }
}

extern "C" void kernel_launch(void* const* d_in, const int* in_sizes, int n_in,
                              void* d_out, int out_size, void* d_ws, size_t ws_size,
                              hipStream_t stream) {
    const float* x  = (const float*)d_in[0];
    const int* src  = (const int*)d_in[1];
    const int* dst  = (const int*)d_in[2];
    const float* W1 = (const float*)d_in[3];
    const float* b1 = (const float*)d_in[4];
    const float* W2 = (const float*)d_in[5];
    const float* b2 = (const float*)d_in[6];
    float* out = (float*)d_out;
    const int E = in_sizes[1];

    char* ws = (char*)d_ws;
    float* norm_s    = (float*)(ws + 0);                // 32KB
    int*   cnt       = (int*)(ws + (32 << 10));         // 64KB (cnt_s | cnt_d)
    int*   row_start = (int*)(ws + (96 << 10));         // 8193 ints
    int*   cursor    = (int*)(ws + (132 << 10));        // 32KB
    int*   csr_src   = (int*)(ws + (164 << 10));        // E ints = 1MB
    char*  big       = ws + (164 << 10) + ((size_t)E * 4);
    float* bufA      = (float*)big;                     // 4MB (y1)
    float* bufB      = (float*)(big + (4 << 20));       // 4MB (y2)
    __hip_bfloat16* h2bf = (__hip_bfloat16*)(big + (8 << 20));  // 2MB

    // zero degree counters (kernel, not memset — in-graph fill nodes are slow)
    k_zero<<<64, 256, 0, stream>>>(cnt, 2 * NNODES);

    // degrees, norms, CSR (graph shared by both layers)
    k_deg_int<<<(E + 255) / 256, 256, 0, stream>>>(src, dst, cnt, E);
    k_scan_norms<<<1, 256, 0, stream>>>(cnt, norm_s, row_start, cursor, NNODES);
    k_fill<<<(E + 255) / 256, 256, 0, stream>>>(src, dst, cursor, csr_src, E);

    // layer 1 linear: y1 = (x@W1)*ns
    k_lin<256><<<NNODES / 16, 256, 0, stream>>>(x, W1, norm_s, bufA);
    // fused: h1 = relu(gather(y1)*nd + b1) [LDS-local]; y2 = (h1@W2)*ns
    k_gatlin<<<NNODES / 8, 256, 0, stream>>>(bufA, row_start, csr_src, b1, W2, norm_s, bufB);
    // layer 2 gather: h2 = gather(y2)*nd + b2 -> bf16
    k_gat2<<<NNODES / 8, 256, 0, stream>>>(bufB, row_start, csr_src, b2, (unsigned short*)h2bf);

    // decode: out = sigmoid(h2 @ h2^T)
    k_decode<<<dim3(64, 64), 256, 0, stream>>>(h2bf, out);
}